// Round 3
// baseline (290.582 us; speedup 1.0000x reference)
//
#include <hip/hip_runtime.h>
#include <hip/hip_bf16.h>

#define ES 128
#define KN 50

__global__ __launch_bounds__(256) void onehop_attn_kernel(
    const float* __restrict__ ent,
    const float* __restrict__ rel,
    const float* __restrict__ Wb,
    const float* __restrict__ W1,
    const float* __restrict__ b1,
    const float* __restrict__ W2,
    const float* __restrict__ b2,
    const int*  __restrict__ hidx,
    const int*  __restrict__ tidx,
    const int*  __restrict__ conn,
    float* __restrict__ out,
    int num_ent, int num_rel)
{
    __shared__ alignas(16) float e_s[2][ES];     // [0]=h_e, [1]=t_e
    __shared__ alignas(16) float ws_s[ES];       // W_bil @ (t_e - h_e)
    __shared__ alignas(16) float sc_s[2][KN];    // raw scores
    __shared__ alignas(16) float att_s[2][KN];   // softmax weights
    __shared__ alignas(16) int   cid_s[2][KN];   // conn_rel indices
    __shared__ alignas(16) float agg_s[2][ES];   // attention-weighted aggregate

    const int pair = blockIdx.x;
    const int tid  = threadIdx.x;
    const int side = tid >> 7;       // 0 = head, 1 = tail
    const int d    = tid & (ES - 1);

    int eid = (side == 0) ? hidx[pair] : tidx[pair];
    eid = min(max(eid, 0), num_ent - 1);          // defensive clamp

    // Gather entity embeddings (coalesced: lane = d) + conn indices
    e_s[side][d] = ent[eid * ES + d];
    if (d < KN) {
        int c = conn[eid * KN + d];
        cid_s[side][d] = min(max(c, 0), num_rel - 1);
    }
    __syncthreads();

    // ws[i] = sum_j W_bil[i][j] * (t_e[j] - h_e[j]) ; threads 0..127, one row each
    if (tid < ES) {
        const float4* wrow = reinterpret_cast<const float4*>(Wb + tid * ES);
        const float4* h4   = reinterpret_cast<const float4*>(e_s[0]);
        const float4* t4   = reinterpret_cast<const float4*>(e_s[1]);
        float acc = 0.f;
        #pragma unroll
        for (int j = 0; j < ES / 4; ++j) {
            float4 w  = wrow[j];
            float4 hv = h4[j];
            float4 tv = t4[j];
            acc += w.x * (tv.x - hv.x) + w.y * (tv.y - hv.y)
                 + w.z * (tv.z - hv.z) + w.w * (tv.w - hv.w);
        }
        ws_s[tid] = acc;
    }
    __syncthreads();

    // scores[side][k] = dot(rel_emb[cid], ws) ; per side, threads d<KN (one k each)
    float score = 0.f;
    if (d < KN) {
        const float4* r4 = reinterpret_cast<const float4*>(rel + cid_s[side][d] * ES);
        const float4* w4 = reinterpret_cast<const float4*>(ws_s);
        float acc = 0.f;
        #pragma unroll
        for (int j = 0; j < ES / 4; ++j) {
            float4 rv = r4[j];
            float4 wv = w4[j];
            acc += rv.x * wv.x + rv.y * wv.y + rv.z * wv.z + rv.w * wv.w;
        }
        score = acc;
        sc_s[side][d] = acc;
    }
    __syncthreads();

    // softmax over K=50 (every thread scans its side's 50 scores; LDS broadcast)
    float mx = -1e30f;
    #pragma unroll
    for (int k = 0; k < KN; ++k) mx = fmaxf(mx, sc_s[side][k]);
    float sum = 0.f;
    #pragma unroll
    for (int k = 0; k < KN; ++k) sum += __expf(sc_s[side][k] - mx);
    if (d < KN) att_s[side][d] = __expf(score - mx) / sum;
    __syncthreads();

    // aggregate: agg[side][d] = sum_k att[k] * rel_emb[cid[k]][d]  (coalesced over d)
    float acc = 0.f;
    for (int k = 0; k < KN; ++k) {
        acc += att_s[side][k] * rel[cid_s[side][k] * ES + d];
    }
    agg_s[side][d] = acc;
    __syncthreads();

    // out[i] = relu(agg @ W1.T + b1 + e @ W2.T + b2) ; thread (side, i=d), one row each
    float o = b1[d] + b2[d];
    const float4* w1r = reinterpret_cast<const float4*>(W1 + d * ES);
    const float4* w2r = reinterpret_cast<const float4*>(W2 + d * ES);
    const float4* a4  = reinterpret_cast<const float4*>(agg_s[side]);
    const float4* e4  = reinterpret_cast<const float4*>(e_s[side]);
    #pragma unroll
    for (int j = 0; j < ES / 4; ++j) {
        float4 w1v = w1r[j], w2v = w2r[j], av = a4[j], ev = e4[j];
        o += w1v.x * av.x + w1v.y * av.y + w1v.z * av.z + w1v.w * av.w;
        o += w2v.x * ev.x + w2v.y * ev.y + w2v.z * ev.z + w2v.w * ev.w;
    }
    o = fmaxf(o, 0.f);
    out[(pair * 2 + side) * ES + d] = o;   // f32 output per harness contract
}

extern "C" void kernel_launch(void* const* d_in, const int* in_sizes, int n_in,
                              void* d_out, int out_size, void* d_ws, size_t ws_size,
                              hipStream_t stream) {
    const float* ent = (const float*)d_in[0];
    const float* rel = (const float*)d_in[1];
    const float* Wb  = (const float*)d_in[2];
    const float* W1  = (const float*)d_in[3];
    const float* b1  = (const float*)d_in[4];
    const float* W2  = (const float*)d_in[5];
    const float* b2  = (const float*)d_in[6];
    const int* hidx  = (const int*)d_in[7];
    const int* tidx  = (const int*)d_in[8];
    const int* conn  = (const int*)d_in[9];
    float* out = (float*)d_out;

    const int npair   = in_sizes[7];          // B * N = 4096
    const int num_ent = in_sizes[0] / ES;     // 100000
    const int num_rel = in_sizes[1] / ES;     // 200

    onehop_attn_kernel<<<npair, 256, 0, stream>>>(
        ent, rel, Wb, W1, b1, W2, b2, hidx, tidx, conn, out, num_ent, num_rel);
}

// Round 5
// 279.479 us; speedup vs baseline: 1.0397x; 1.0397x over previous
//
#include <hip/hip_runtime.h>

#define ES  128
#define KN  50
#define PAD 129          // rel row pad (floats) -> conflict-free LDS access
#define NROW (2*KN)      // 100 staged rel rows (head + tail)

__global__ __launch_bounds__(256, 2) void onehop_attn_kernel(
    const float* __restrict__ ent, const float* __restrict__ rel,
    const float* __restrict__ Wb,  const float* __restrict__ W1,
    const float* __restrict__ b1,  const float* __restrict__ W2,
    const float* __restrict__ b2,
    const int* __restrict__ hidx, const int* __restrict__ tidx,
    const int* __restrict__ conn,
    float* __restrict__ out, int num_ent, int num_rel)
{
    __shared__ float rel_s[NROW * PAD];   // 51.6 KB gathered rel rows
    __shared__ float e_s[2][ES];          // h_e, t_e
    __shared__ float ws_s[ES];            // Wb @ (t_e - h_e)
    __shared__ float sc_s[2][64];         // scores (padded to 64)
    __shared__ float att_s[2][64];        // softmax weights
    __shared__ int   cid_s[2][64];        // conn indices
    __shared__ float agg_s[2][ES];        // attention aggregate
    __shared__ float o_s[256];            // raw outputs pre-bias

    const int pair = blockIdx.x;
    const int tid  = threadIdx.x;
    const int g    = tid >> 5;            // 32-lane group 0..7
    const int gl   = tid & 31;            // lane within group
    const int side = tid >> 7;            // 0=head, 1=tail
    const int d    = tid & (ES - 1);

    int eid = (side == 0) ? hidx[pair] : tidx[pair];
    eid = min(max(eid, 0), num_ent - 1);

    // P0: gather entity rows (coalesced) + conn indices
    e_s[side][d] = ent[eid * ES + d];
    if (d < KN) {
        int c = conn[eid * KN + d];
        cid_s[side][d] = min(max(c, 0), num_rel - 1);
    }
    __syncthreads();

    // P2: ws[i] = sum_j Wb[i][j]*(t[j]-h[j]) — group-per-row, dense row reads
    {
        const float4* Wb4 = reinterpret_cast<const float4*>(Wb);
        const float4* h4  = reinterpret_cast<const float4*>(e_s[0]);
        const float4* t4  = reinterpret_cast<const float4*>(e_s[1]);
        #pragma unroll 4
        for (int i = g; i < ES; i += 8) {
            float4 w  = Wb4[i * 32 + gl];
            float4 hv = h4[gl], tv = t4[gl];
            float p = w.x*(tv.x-hv.x) + w.y*(tv.y-hv.y)
                    + w.z*(tv.z-hv.z) + w.w*(tv.w-hv.w);
            p += __shfl_xor(p, 1);  p += __shfl_xor(p, 2);
            p += __shfl_xor(p, 4);  p += __shfl_xor(p, 8);
            p += __shfl_xor(p, 16);
            if (gl == 0) ws_s[i] = p;
        }
    }
    // P1: stage rel rows in LDS (strided lanes -> conflict-free writes)
    for (int r = g; r < NROW; r += 8) {
        int rs = (r >= KN) ? 1 : 0;
        int rk = r - rs * KN;
        const float* src = rel + cid_s[rs][rk] * ES;
        #pragma unroll
        for (int m = 0; m < 4; ++m)
            rel_s[r * PAD + m * 32 + gl] = src[m * 32 + gl];
    }
    __syncthreads();

    // P3: scores — thread (k, half) over staged rows; conflict-free (PAD=129)
    {
        int idx = tid & 127;
        int k = idx >> 1, h = idx & 1;
        float v = 0.f;
        if (k < KN) {
            const float* row = rel_s + (side * KN + k) * PAD + h * 64;
            const float* w   = ws_s + h * 64;
            #pragma unroll
            for (int i = 0; i < 64; ++i) v += row[i] * w[i];
        }
        v += __shfl_xor(v, 1);
        if (k < KN && (idx & 1) == 0) sc_s[side][k] = v;
    }
    __syncthreads();

    // softmax (broadcast LDS scan, 50 elems)
    float mx = -1e30f;
    #pragma unroll
    for (int k = 0; k < KN; ++k) mx = fmaxf(mx, sc_s[side][k]);
    float sum = 0.f;
    #pragma unroll
    for (int k = 0; k < KN; ++k) sum += __expf(sc_s[side][k] - mx);
    float rinv = 1.f / sum;
    {
        int idx = tid & 127;
        int k = idx >> 1;
        if (k < KN && (idx & 1) == 0)
            att_s[side][k] = __expf(sc_s[side][k] - mx) * rinv;
    }
    __syncthreads();

    // P4: aggregate agg[d] = sum_k att[k]*rel[k][d] — conflict-free lanes over d
    {
        float acc = 0.f;
        #pragma unroll
        for (int k = 0; k < KN; ++k)
            acc += att_s[side][k] * rel_s[(side * KN + k) * PAD + d];
        agg_s[side][d] = acc;
    }
    __syncthreads();

    // P5: out_raw[r] = agg@W1[rd] + e@W2[rd] — group-per-row, dense reads
    {
        const float4* W14 = reinterpret_cast<const float4*>(W1);
        const float4* W24 = reinterpret_cast<const float4*>(W2);
        #pragma unroll 4
        for (int r = g; r < 256; r += 8) {
            int rs = r >> 7, rd = r & 127;
            float4 w1v = W14[rd * 32 + gl];
            float4 w2v = W24[rd * 32 + gl];
            const float4* a4 = reinterpret_cast<const float4*>(agg_s[rs]);
            const float4* e4 = reinterpret_cast<const float4*>(e_s[rs]);
            float4 av = a4[gl], ev = e4[gl];
            float p = w1v.x*av.x + w1v.y*av.y + w1v.z*av.z + w1v.w*av.w
                    + w2v.x*ev.x + w2v.y*ev.y + w2v.z*ev.z + w2v.w*ev.w;
            p += __shfl_xor(p, 1);  p += __shfl_xor(p, 2);
            p += __shfl_xor(p, 4);  p += __shfl_xor(p, 8);
            p += __shfl_xor(p, 16);
            if (gl == 0) o_s[r] = p;
        }
    }
    __syncthreads();

    // bias + relu + coalesced store
    float o = o_s[tid] + b1[d] + b2[d];
    out[pair * 256 + tid] = fmaxf(o, 0.f);
}

extern "C" void kernel_launch(void* const* d_in, const int* in_sizes, int n_in,
                              void* d_out, int out_size, void* d_ws, size_t ws_size,
                              hipStream_t stream) {
    const float* ent = (const float*)d_in[0];
    const float* rel = (const float*)d_in[1];
    const float* Wb  = (const float*)d_in[2];
    const float* W1  = (const float*)d_in[3];
    const float* b1  = (const float*)d_in[4];
    const float* W2  = (const float*)d_in[5];
    const float* b2  = (const float*)d_in[6];
    const int* hidx  = (const int*)d_in[7];
    const int* tidx  = (const int*)d_in[8];
    const int* conn  = (const int*)d_in[9];
    float* out = (float*)d_out;

    const int npair   = in_sizes[7];          // 4096
    const int num_ent = in_sizes[0] / ES;     // 100000
    const int num_rel = in_sizes[1] / ES;     // 200

    onehop_attn_kernel<<<npair, 256, 0, stream>>>(
        ent, rel, Wb, W1, b1, W2, b2, hidx, tidx, conn, out, num_ent, num_rel);
}

// Round 6
// 185.071 us; speedup vs baseline: 1.5701x; 1.5101x over previous
//
#include <hip/hip_runtime.h>

#define ES 128
#define KN 50

// Prep: build transposed weights in d_ws.
//   wt[0      .. 16384) : WbT  (WbT[j*128+i] = Wb[i*128+j])
//   wt[16384  .. 49152) : WT2  (rows j<128: W1^T row j ; rows 128..255: W2^T row j-128)
__global__ __launch_bounds__(256) void prep_transpose(
    const float* __restrict__ Wb, const float* __restrict__ W1,
    const float* __restrict__ W2, float* __restrict__ wt)
{
    int n = blockIdx.x * 256 + threadIdx.x;   // 0..49151
    int m = n >> 14;                          // 0:Wb 1:W1 2:W2
    int r = (n >> 7) & 127;                   // transposed row j
    int c = n & 127;                          // transposed col i
    const float* src = (m == 0) ? Wb : ((m == 1) ? W1 : W2);
    wt[n] = src[c * ES + r];
}

// One wave (64 lanes) handles 2 pairs end-to-end. No __syncthreads anywhere:
// cross-lane via shuffles; per-wave LDS scratch has only same-wave dependencies.
__global__ __launch_bounds__(64) void onehop_wave_kernel(
    const float* __restrict__ ent, const float* __restrict__ rel,
    const float* __restrict__ b1,  const float* __restrict__ b2,
    const int* __restrict__ hidx,  const int* __restrict__ tidx,
    const int* __restrict__ conn,
    const float* __restrict__ WbT, const float* __restrict__ WT2,
    float* __restrict__ out, int npair, int num_ent, int num_rel)
{
    __shared__ float coef[4][256];   // [2p+side][j]: j<128 = agg/l ; j>=128 = e row
    __shared__ float wrbuf[ES];      // weak-rel scratch (sequentially reused by p=0,1)

    const int lane  = threadIdx.x;   // 0..63, lane holds dims (2*lane, 2*lane+1)
    const int pair0 = blockIdx.x * 2;

    #pragma unroll
    for (int p = 0; p < 2; ++p) {
        const int pair = pair0 + p;
        if (pair < npair) {
            int hid = min(max(hidx[pair], 0), num_ent - 1);
            int tdi = min(max(tidx[pair], 0), num_ent - 1);

            float2 he = *(const float2*)(ent + (size_t)hid * ES + 2 * lane);
            float2 te = *(const float2*)(ent + (size_t)tdi * ES + 2 * lane);
            int kl = min(lane, KN - 1);
            int ch_id = min(max(conn[(size_t)hid * KN + kl], 0), num_rel - 1);
            int ct_id = min(max(conn[(size_t)tdi * KN + kl], 0), num_rel - 1);

            *(float2*)(&wrbuf[2 * lane]) = make_float2(te.x - he.x, te.y - he.y);
            *(float2*)(&coef[2 * p][128 + 2 * lane])     = he;  // W2 coefs
            *(float2*)(&coef[2 * p + 1][128 + 2 * lane]) = te;

            // ws[i] = sum_j wr[j] * WbT[j][i]  — coalesced row scan, LDS broadcast coef
            float2 a0 = make_float2(0.f, 0.f), a1 = make_float2(0.f, 0.f);
            #pragma unroll 4
            for (int j = 0; j < ES; j += 2) {
                float2 wj = *(const float2*)(&wrbuf[j]);                         // broadcast
                float2 r0 = *(const float2*)(WbT + (size_t)j * ES + 2 * lane);   // 512B row
                float2 r1 = *(const float2*)(WbT + (size_t)(j + 1) * ES + 2 * lane);
                a0.x += wj.x * r0.x; a0.y += wj.x * r0.y;
                a1.x += wj.y * r1.x; a1.y += wj.y * r1.y;
            }
            const float2 ws2 = make_float2(a0.x + a1.x, a0.y + a1.y);

            // fused scores + online softmax + aggregate (head & tail interleaved);
            // rel rows read ONCE, coalesced; score via 6-step butterfly allreduce
            float mh = -1e30f, lh = 0.f, mt = -1e30f, lt = 0.f;
            float2 aggh = make_float2(0.f, 0.f), aggt = make_float2(0.f, 0.f);
            for (int k = 0; k < KN; ++k) {
                int rh = __shfl(ch_id, k);
                int rt = __shfl(ct_id, k);
                float2 vh = *(const float2*)(rel + (size_t)rh * ES + 2 * lane);
                float2 vt = *(const float2*)(rel + (size_t)rt * ES + 2 * lane);
                float ph = vh.x * ws2.x + vh.y * ws2.y;
                float pt = vt.x * ws2.x + vt.y * ws2.y;
                #pragma unroll
                for (int s = 1; s < 64; s <<= 1) {
                    ph += __shfl_xor(ph, s);
                    pt += __shfl_xor(pt, s);
                }
                float mn    = fmaxf(mh, ph);
                float eh    = __expf(ph - mn);
                float cor_h = __expf(mh - mn);
                lh = lh * cor_h + eh;
                aggh.x = aggh.x * cor_h + eh * vh.x;
                aggh.y = aggh.y * cor_h + eh * vh.y;
                mh = mn;
                mn          = fmaxf(mt, pt);
                float et    = __expf(pt - mn);
                float cor_t = __expf(mt - mn);
                lt = lt * cor_t + et;
                aggt.x = aggt.x * cor_t + et * vt.x;
                aggt.y = aggt.y * cor_t + et * vt.y;
                mt = mn;
            }
            float rlh = 1.f / lh, rlt = 1.f / lt;
            *(float2*)(&coef[2 * p][2 * lane])     = make_float2(aggh.x * rlh, aggh.y * rlh);
            *(float2*)(&coef[2 * p + 1][2 * lane]) = make_float2(aggt.x * rlt, aggt.y * rlt);
        }
    }

    // Final: out[i] = relu( sum_{j<128} agg[j]*W1T[j][i] + sum_{j<128} e[j]*W2T[j][i] + b1+b2 )
    // One W^T row read serves all 4 outputs (2 pairs x 2 sides).
    float2 h0a = make_float2(0.f, 0.f), h0b = make_float2(0.f, 0.f);
    float2 t0a = make_float2(0.f, 0.f), t0b = make_float2(0.f, 0.f);
    float2 h1a = make_float2(0.f, 0.f), h1b = make_float2(0.f, 0.f);
    float2 t1a = make_float2(0.f, 0.f), t1b = make_float2(0.f, 0.f);
    #pragma unroll 2
    for (int j = 0; j < 2 * ES; j += 2) {
        float2 r0 = *(const float2*)(WT2 + (size_t)j * ES + 2 * lane);
        float2 r1 = *(const float2*)(WT2 + (size_t)(j + 1) * ES + 2 * lane);
        float2 c0 = *(const float2*)(&coef[0][j]);   // LDS broadcast reads
        float2 c1 = *(const float2*)(&coef[1][j]);
        float2 c2 = *(const float2*)(&coef[2][j]);
        float2 c3 = *(const float2*)(&coef[3][j]);
        h0a.x += c0.x * r0.x; h0a.y += c0.x * r0.y;
        h0b.x += c0.y * r1.x; h0b.y += c0.y * r1.y;
        t0a.x += c1.x * r0.x; t0a.y += c1.x * r0.y;
        t0b.x += c1.y * r1.x; t0b.y += c1.y * r1.y;
        h1a.x += c2.x * r0.x; h1a.y += c2.x * r0.y;
        h1b.x += c2.y * r1.x; h1b.y += c2.y * r1.y;
        t1a.x += c3.x * r0.x; t1a.y += c3.x * r0.y;
        t1b.x += c3.y * r1.x; t1b.y += c3.y * r1.y;
    }
    float2 b1v = *(const float2*)(b1 + 2 * lane);
    float2 b2v = *(const float2*)(b2 + 2 * lane);
    float bx = b1v.x + b2v.x, by = b1v.y + b2v.y;

    {
        float2 o;
        o.x = fmaxf(h0a.x + h0b.x + bx, 0.f);
        o.y = fmaxf(h0a.y + h0b.y + by, 0.f);
        *(float2*)(out + ((size_t)pair0 * 2 + 0) * ES + 2 * lane) = o;
        o.x = fmaxf(t0a.x + t0b.x + bx, 0.f);
        o.y = fmaxf(t0a.y + t0b.y + by, 0.f);
        *(float2*)(out + ((size_t)pair0 * 2 + 1) * ES + 2 * lane) = o;
    }
    if (pair0 + 1 < npair) {
        float2 o;
        o.x = fmaxf(h1a.x + h1b.x + bx, 0.f);
        o.y = fmaxf(h1a.y + h1b.y + by, 0.f);
        *(float2*)(out + ((size_t)(pair0 + 1) * 2 + 0) * ES + 2 * lane) = o;
        o.x = fmaxf(t1a.x + t1b.x + bx, 0.f);
        o.y = fmaxf(t1a.y + t1b.y + by, 0.f);
        *(float2*)(out + ((size_t)(pair0 + 1) * 2 + 1) * ES + 2 * lane) = o;
    }
}

extern "C" void kernel_launch(void* const* d_in, const int* in_sizes, int n_in,
                              void* d_out, int out_size, void* d_ws, size_t ws_size,
                              hipStream_t stream) {
    const float* ent = (const float*)d_in[0];
    const float* rel = (const float*)d_in[1];
    const float* Wb  = (const float*)d_in[2];
    const float* W1  = (const float*)d_in[3];
    const float* b1  = (const float*)d_in[4];
    const float* W2  = (const float*)d_in[5];
    const float* b2  = (const float*)d_in[6];
    const int* hidx  = (const int*)d_in[7];
    const int* tidx  = (const int*)d_in[8];
    const int* conn  = (const int*)d_in[9];
    float* out = (float*)d_out;

    const int npair   = in_sizes[7];          // 4096
    const int num_ent = in_sizes[0] / ES;     // 100000
    const int num_rel = in_sizes[1] / ES;     // 200

    float* wt = (float*)d_ws;                 // needs 192 KB of scratch
    prep_transpose<<<192, 256, 0, stream>>>(Wb, W1, W2, wt);

    const int nblocks = (npair + 1) / 2;      // one wave per 2 pairs
    onehop_wave_kernel<<<nblocks, 64, 0, stream>>>(
        ent, rel, b1, b2, hidx, tidx, conn,
        wt, wt + 16384, out, npair, num_ent, num_rel);
}

// Round 8
// 159.416 us; speedup vs baseline: 1.8228x; 1.1609x over previous
//
#include <hip/hip_runtime.h>

#define ES 128
#define KN 50

// wt layout (PROVEN 192 KB, round 6): [0,16384) WbT ; [16384,49152) W1^T then W2^T
__global__ __launch_bounds__(256) void prep_transpose(
    const float* __restrict__ Wb, const float* __restrict__ W1,
    const float* __restrict__ W2, float* __restrict__ wt)
{
    int n = blockIdx.x * 256 + threadIdx.x;   // 0..49151
    int m = n >> 14;                          // 0:Wb 1:W1 2:W2
    int r = (n >> 7) & 127;                   // transposed row j
    int c = n & 127;                          // transposed col i
    const float* src = (m == 0) ? Wb : ((m == 1) ? W1 : W2);
    wt[n] = src[c * ES + r];
}

// Issue 10 score-row loads from rel (head rows -> lanes 0-31, tail -> 32-63)
#define LOADC(BUF, C) do {                                                   \
    _Pragma("unroll") for (int u = 0; u < 10; ++u) {                         \
        int k = (C) * 10 + u;                                                \
        int cid = (k < 32) ? cidA : cidB;                                    \
        int row = __shfl(cid, hb + (k & 31));                                \
        BUF[u] = *(const float4*)(rel + (size_t)row * ES + 4 * q);           \
    } } while (0)

// Dot vs ws fragment + 10-wide batched 5-step butterfly (within each half)
#define REDUCE(BUF, C) do {                                                  \
    float pv[10];                                                            \
    _Pragma("unroll") for (int u = 0; u < 10; ++u)                           \
        pv[u] = BUF[u].x*ws4.x + BUF[u].y*ws4.y + BUF[u].z*ws4.z + BUF[u].w*ws4.w;\
    _Pragma("unroll") for (int s = 1; s < 32; s <<= 1)                       \
        { _Pragma("unroll") for (int u = 0; u < 10; ++u)                     \
            pv[u] += __shfl_xor(pv[u], s); }                                 \
    _Pragma("unroll") for (int u = 0; u < 10; ++u) {                         \
        int k = (C) * 10 + u;                                                \
        if (k < 32) s1 = (q == k)      ? pv[u] : s1;                         \
        else        s2 = (q == k - 32) ? pv[u] : s2;                         \
    } } while (0)

#define XADD(a) do { a.x += __shfl_xor(a.x, 32); a.y += __shfl_xor(a.y, 32); \
                     a.z += __shfl_xor(a.z, 32); a.w += __shfl_xor(a.w, 32); } while (0)

__global__ __launch_bounds__(64) void onehop_main(
    const float* __restrict__ ent, const float* __restrict__ rel,
    const float* __restrict__ b1, const float* __restrict__ b2,
    const int* __restrict__ hidx, const int* __restrict__ tidx,
    const int* __restrict__ conn,
    const float* __restrict__ WbT, const float* __restrict__ WT2,
    float* __restrict__ out, int npair, int num_ent, int num_rel)
{
    __shared__ float coef[4][2 * ES];   // [2p+side][j<128: agg ; j>=128: ent row]
    __shared__ float wrbuf[2][ES];      // weak-rel per pair (broadcast source)

    const int lane = threadIdx.x;
    const int q    = lane & 31;
    const int hi   = lane >> 5;         // 0 = head half, 1 = tail half
    const int hb   = lane & 32;
    const int pair0 = blockIdx.x * 2;
    const int pairB = min(pair0 + 1, npair - 1);

    // hoisted gathers for BOTH pairs (8 loads in flight before any compute)
    int hid0 = min(max(hidx[pair0], 0), num_ent - 1);
    int tdi0 = min(max(tidx[pair0], 0), num_ent - 1);
    int hid1 = min(max(hidx[pairB], 0), num_ent - 1);
    int tdi1 = min(max(tidx[pairB], 0), num_ent - 1);

    float4 he0 = *(const float4*)(ent + (size_t)hid0 * ES + 4 * q);
    float4 te0 = *(const float4*)(ent + (size_t)tdi0 * ES + 4 * q);
    float4 he1 = *(const float4*)(ent + (size_t)hid1 * ES + 4 * q);
    float4 te1 = *(const float4*)(ent + (size_t)tdi1 * ES + 4 * q);

    const int cl = min(lane, KN - 1);
    int ch0 = min(max(conn[(size_t)hid0 * KN + cl], 0), num_rel - 1);
    int ct0 = min(max(conn[(size_t)tdi0 * KN + cl], 0), num_rel - 1);
    int ch1 = min(max(conn[(size_t)hid1 * KN + cl], 0), num_rel - 1);
    int ct1 = min(max(conn[(size_t)tdi1 * KN + cl], 0), num_rel - 1);

    #pragma unroll
    for (int p = 0; p < 2; ++p) {
        float4 he = p ? he1 : he0, te = p ? te1 : te0;
        int    ch = p ? ch1 : ch0, ct = p ? ct1 : ct0;

        float4 wr;
        wr.x = te.x - he.x; wr.y = te.y - he.y;
        wr.z = te.z - he.z; wr.w = te.w - he.w;
        *(float4*)(&wrbuf[p][4 * q]) = wr;              // both halves write same vals
        *(float4*)(&coef[2 * p + hi][ES + 4 * q]) = hi ? te : he;  // W2 coefs

        int ctq  = __shfl(ct, q);
        int cidA = hi ? ctq : ch;                       // k = 0..31 of own side
        int cB_l = __shfl(ch, q + 32);
        int cB_h = __shfl(ct, q + 32);
        int cidB = hi ? cB_h : cB_l;                    // k = 32..49 of own side

        // ws fragment: ws[4q..4q+3] = sum_j wr[j] * WbT[j][4q..] — streaming, no reduce
        float4 ws4 = {0.f, 0.f, 0.f, 0.f};
        #pragma unroll 8
        for (int j = 0; j < ES; ++j) {
            float  wj = wrbuf[p][j];                    // LDS broadcast (conflict-free)
            float4 wv = *(const float4*)(WbT + (size_t)j * ES + 4 * q);
            ws4.x += wj * wv.x; ws4.y += wj * wv.y;
            ws4.z += wj * wv.z; ws4.w += wj * wv.w;
        }

        // Phase S: all 50 scores, 2-deep pipelined chunks of 10
        float s1 = -1e30f, s2 = -1e30f;
        {
            float4 bufA[10], bufB[10];
            LOADC(bufA, 0); LOADC(bufB, 1);
            REDUCE(bufA, 0); LOADC(bufA, 2);
            REDUCE(bufB, 1); LOADC(bufB, 3);
            REDUCE(bufA, 2); LOADC(bufA, 4);
            REDUCE(bufB, 3);
            REDUCE(bufA, 4);
        }

        // softmax per half
        float m = fmaxf(s1, s2);
        #pragma unroll
        for (int s = 1; s < 32; s <<= 1) m = fmaxf(m, __shfl_xor(m, s));
        float e1 = __expf(s1 - m), e2 = __expf(s2 - m);  // invalid s2 slots -> 0
        float l = e1 + e2;
        #pragma unroll
        for (int s = 1; s < 32; s <<= 1) l += __shfl_xor(l, s);
        float rinv = 1.f / l;
        e1 *= rinv; e2 *= rinv;

        // Phase A: streaming aggregate, no reduction on the path
        float4 agg = {0.f, 0.f, 0.f, 0.f};
        #pragma unroll 10
        for (int k = 0; k < KN; ++k) {
            int src = hb + (k & 31);
            float ev = __shfl((k < 32) ? e1 : e2, src);
            int row  = __shfl((k < 32) ? cidA : cidB, src);
            float4 v = *(const float4*)(rel + (size_t)row * ES + 4 * q);
            agg.x += ev * v.x; agg.y += ev * v.y;
            agg.z += ev * v.z; agg.w += ev * v.w;
        }
        *(float4*)(&coef[2 * p + hi][4 * q]) = agg;
    }

    // Final: 4 outputs share each W^T row; 2 rows per load (even/odd j split)
    float4 a0 = {0,0,0,0}, a1 = {0,0,0,0}, a2 = {0,0,0,0}, a3 = {0,0,0,0};
    #pragma unroll 4
    for (int j = 0; j < 2 * ES; j += 2) {
        float4 w = *(const float4*)(WT2 + (size_t)j * ES + 4 * lane); // row j (lo half) / j+1 (hi half)
        int jl = j + hi;
        float c0 = coef[0][jl], c1 = coef[1][jl];
        float c2 = coef[2][jl], c3 = coef[3][jl];
        a0.x += c0*w.x; a0.y += c0*w.y; a0.z += c0*w.z; a0.w += c0*w.w;
        a1.x += c1*w.x; a1.y += c1*w.y; a1.z += c1*w.z; a1.w += c1*w.w;
        a2.x += c2*w.x; a2.y += c2*w.y; a2.z += c2*w.z; a2.w += c2*w.w;
        a3.x += c3*w.x; a3.y += c3*w.y; a3.z += c3*w.z; a3.w += c3*w.w;
    }
    XADD(a0); XADD(a1); XADD(a2); XADD(a3);

    float4 bv1 = *(const float4*)(b1 + 4 * q);
    float4 bv2 = *(const float4*)(b2 + 4 * q);
    float4 bb;
    bb.x = bv1.x + bv2.x; bb.y = bv1.y + bv2.y;
    bb.z = bv1.z + bv2.z; bb.w = bv1.w + bv2.w;

    float4 oh, ot, o;
    oh.x = fmaxf(a0.x + bb.x, 0.f); oh.y = fmaxf(a0.y + bb.y, 0.f);
    oh.z = fmaxf(a0.z + bb.z, 0.f); oh.w = fmaxf(a0.w + bb.w, 0.f);
    ot.x = fmaxf(a1.x + bb.x, 0.f); ot.y = fmaxf(a1.y + bb.y, 0.f);
    ot.z = fmaxf(a1.z + bb.z, 0.f); ot.w = fmaxf(a1.w + bb.w, 0.f);
    o = hi ? ot : oh;
    *(float4*)(out + (size_t)(pair0 * 2 + hi) * ES + 4 * q) = o;

    if (pair0 + 1 < npair) {
        oh.x = fmaxf(a2.x + bb.x, 0.f); oh.y = fmaxf(a2.y + bb.y, 0.f);
        oh.z = fmaxf(a2.z + bb.z, 0.f); oh.w = fmaxf(a2.w + bb.w, 0.f);
        ot.x = fmaxf(a3.x + bb.x, 0.f); ot.y = fmaxf(a3.y + bb.y, 0.f);
        ot.z = fmaxf(a3.z + bb.z, 0.f); ot.w = fmaxf(a3.w + bb.w, 0.f);
        o = hi ? ot : oh;
        *(float4*)(out + (size_t)((pair0 + 1) * 2 + hi) * ES + 4 * q) = o;
    }
}

extern "C" void kernel_launch(void* const* d_in, const int* in_sizes, int n_in,
                              void* d_out, int out_size, void* d_ws, size_t ws_size,
                              hipStream_t stream) {
    const float* ent = (const float*)d_in[0];
    const float* rel = (const float*)d_in[1];
    const float* Wb  = (const float*)d_in[2];
    const float* W1  = (const float*)d_in[3];
    const float* b1  = (const float*)d_in[4];
    const float* W2  = (const float*)d_in[5];
    const float* b2  = (const float*)d_in[6];
    const int* hidx  = (const int*)d_in[7];
    const int* tidx  = (const int*)d_in[8];
    const int* conn  = (const int*)d_in[9];
    float* out = (float*)d_out;

    const int npair   = in_sizes[7];          // 4096
    const int num_ent = in_sizes[0] / ES;     // 100000
    const int num_rel = in_sizes[1] / ES;     // 200

    float* wt = (float*)d_ws;                 // 192 KB (proven to fit in round 6)
    prep_transpose<<<192, 256, 0, stream>>>(Wb, W1, W2, wt);

    const int nblocks = (npair + 1) / 2;      // one wave per 2 pairs
    onehop_main<<<nblocks, 64, 0, stream>>>(
        ent, rel, b1, b2, hidx, tidx, conn,
        wt, wt + 16384, out, npair, num_ent, num_rel);
}

// Round 9
// 146.740 us; speedup vs baseline: 1.9803x; 1.0864x over previous
//
#include <hip/hip_runtime.h>

#define ES 128
#define KN 50

__device__ __forceinline__ unsigned short f32_to_bf16_rne(float f) {
    unsigned u = __float_as_uint(f);
    unsigned r = u + 0x7FFF + ((u >> 16) & 1);
    return (unsigned short)(r >> 16);
}
__device__ __forceinline__ float bf16_to_f32(unsigned short u) {
    return __uint_as_float(((unsigned)u) << 16);
}

// RWb[r][j] = sum_i rel[r][i] * Wb[i][j]   (folds bilinear matvec into rel rows)
__global__ __launch_bounds__(128) void prep_rwb(
    const float* __restrict__ rel, const float* __restrict__ Wb,
    float* __restrict__ rwb)
{
    const int r = blockIdx.x, j = threadIdx.x;
    float acc = 0.f;
    #pragma unroll 8
    for (int i = 0; i < ES; ++i)
        acc += rel[r * ES + i] * Wb[i * ES + j];
    rwb[r * ES + j] = acc;
}

// WTB row j (bf16): j<128 -> W1^T row j ; j>=128 -> W2^T row j-128
__global__ __launch_bounds__(256) void prep_wtbf(
    const float* __restrict__ W1, const float* __restrict__ W2,
    unsigned short* __restrict__ wtb)
{
    int n = blockIdx.x * 256 + threadIdx.x;   // 0..32767
    int j = n >> 7, c = n & 127;
    const float* src = (j < ES) ? W1 : W2;
    wtb[n] = f32_to_bf16_rne(src[c * ES + (j & 127)]);
}

// Issue 10 score-row loads from RWb (own side's rows per half-wave)
#define LOADC(BUF, C) do {                                                   \
    _Pragma("unroll") for (int u = 0; u < 10; ++u) {                         \
        int k = (C) * 10 + u;                                                \
        int cid = (k < 32) ? cidA : cidB;                                    \
        int row = __shfl(cid, hb + (k & 31));                                \
        BUF[u] = *(const float4*)(RWb + (size_t)row * ES + 4 * q);           \
    } } while (0)

// Dot vs wr fragment + 10-wide batched 5-step butterfly (within each half)
#define REDUCE(BUF, C) do {                                                  \
    float pv[10];                                                            \
    _Pragma("unroll") for (int u = 0; u < 10; ++u)                           \
        pv[u] = BUF[u].x*wr.x + BUF[u].y*wr.y + BUF[u].z*wr.z + BUF[u].w*wr.w;\
    _Pragma("unroll") for (int s = 1; s < 32; s <<= 1)                       \
        { _Pragma("unroll") for (int u = 0; u < 10; ++u)                     \
            pv[u] += __shfl_xor(pv[u], s); }                                 \
    _Pragma("unroll") for (int u = 0; u < 10; ++u) {                         \
        int k = (C) * 10 + u;                                                \
        if (k < 32) s1 = (q == k)      ? pv[u] : s1;                         \
        else        s2 = (q == k - 32) ? pv[u] : s2;                         \
    } } while (0)

#define XADD(a) do { a.x += __shfl_xor(a.x, 32); a.y += __shfl_xor(a.y, 32); \
                     a.z += __shfl_xor(a.z, 32); a.w += __shfl_xor(a.w, 32); } while (0)

// 2 waves/block, 1 pair/wave. Final linear split by j-half across the waves:
// wave0: W1·agg partial (j 0..127), wave1: W2·ent partial (j 128..255), LDS combine.
__global__ __launch_bounds__(128, 4) void onehop_main(
    const float* __restrict__ ent, const float* __restrict__ rel,
    const float* __restrict__ b1, const float* __restrict__ b2,
    const int* __restrict__ hidx, const int* __restrict__ tidx,
    const int* __restrict__ conn,
    const float* __restrict__ RWb, const unsigned short* __restrict__ WTB,
    float* __restrict__ out, int npair, int num_ent, int num_rel)
{
    __shared__ float coef[4][2 * ES];     // [2w+side][j<128: agg ; j>=128: ent row]
    __shared__ float part[2][4][ES];      // [jhalf][output][col] partials

    const int tid  = threadIdx.x;
    const int wave = tid >> 6;
    const int lane = tid & 63;
    const int q    = lane & 31;
    const int hi   = lane >> 5;           // 0 = head half, 1 = tail half
    const int hb   = lane & 32;

    const int pair = min(blockIdx.x * 2 + wave, npair - 1);

    int hid = min(max(hidx[pair], 0), num_ent - 1);
    int tdi = min(max(tidx[pair], 0), num_ent - 1);

    float4 he = *(const float4*)(ent + (size_t)hid * ES + 4 * q);
    float4 te = *(const float4*)(ent + (size_t)tdi * ES + 4 * q);
    float4 wr;
    wr.x = te.x - he.x; wr.y = te.y - he.y;
    wr.z = te.z - he.z; wr.w = te.w - he.w;
    *(float4*)(&coef[2 * wave + hi][ES + 4 * q]) = hi ? te : he;   // W2 coefs

    const int cl = min(lane, KN - 1);
    int ch = min(max(conn[(size_t)hid * KN + cl], 0), num_rel - 1);
    int ct = min(max(conn[(size_t)tdi * KN + cl], 0), num_rel - 1);
    int ctq  = __shfl(ct, q);
    int cidA = hi ? ctq : ch;                  // own side, k = 0..31
    int cB_l = __shfl(ch, q + 32);
    int cB_h = __shfl(ct, q + 32);
    int cidB = hi ? cB_h : cB_l;               // own side, k = 32..49

    // ---- Phase S: all 50 scores via RWb rows, 2-deep pipelined chunks of 10
    float s1 = -1e30f, s2 = -1e30f;
    {
        float4 bufA[10], bufB[10];
        LOADC(bufA, 0); LOADC(bufB, 1);
        REDUCE(bufA, 0); LOADC(bufA, 2);
        REDUCE(bufB, 1); LOADC(bufB, 3);
        REDUCE(bufA, 2); LOADC(bufA, 4);
        REDUCE(bufB, 3);
        REDUCE(bufA, 4);
    }

    // ---- softmax per half
    float m = fmaxf(s1, s2);
    #pragma unroll
    for (int s = 1; s < 32; s <<= 1) m = fmaxf(m, __shfl_xor(m, s));
    float e1 = __expf(s1 - m), e2 = __expf(s2 - m);   // invalid slots -> 0
    float l = e1 + e2;
    #pragma unroll
    for (int s = 1; s < 32; s <<= 1) l += __shfl_xor(l, s);
    float rinv = 1.f / l;
    e1 *= rinv; e2 *= rinv;

    // ---- Phase A: streaming aggregate from rel rows
    float4 agg = {0.f, 0.f, 0.f, 0.f};
    #pragma unroll 10
    for (int k = 0; k < KN; ++k) {
        int src = hb + (k & 31);
        float ev = __shfl((k < 32) ? e1 : e2, src);
        int row  = __shfl((k < 32) ? cidA : cidB, src);
        float4 v = *(const float4*)(rel + (size_t)row * ES + 4 * q);
        agg.x += ev * v.x; agg.y += ev * v.y;
        agg.z += ev * v.z; agg.w += ev * v.w;
    }
    *(float4*)(&coef[2 * wave + hi][4 * q]) = agg;
    __syncthreads();

    // ---- Final partials: wave w covers j in [128w, 128w+128) for ALL 4 outputs
    const int jbase = wave << 7;
    float4 a0 = {0,0,0,0}, a1 = {0,0,0,0}, a2 = {0,0,0,0}, a3 = {0,0,0,0};
    #pragma unroll 8
    for (int jj = 0; jj < 64; ++jj) {
        int j0 = jbase + 2 * jj;   // lanes<32: row j0 ; lanes>=32: row j0+1
        ushort4 wv = *(const ushort4*)(WTB + (size_t)j0 * ES + 4 * lane);
        float w0 = bf16_to_f32(wv.x), w1 = bf16_to_f32(wv.y);
        float w2 = bf16_to_f32(wv.z), w3 = bf16_to_f32(wv.w);
        int jl = j0 + hi;
        float c0 = coef[0][jl], c1 = coef[1][jl];
        float c2 = coef[2][jl], c3 = coef[3][jl];
        a0.x += c0*w0; a0.y += c0*w1; a0.z += c0*w2; a0.w += c0*w3;
        a1.x += c1*w0; a1.y += c1*w1; a1.z += c1*w2; a1.w += c1*w3;
        a2.x += c2*w0; a2.y += c2*w1; a2.z += c2*w2; a2.w += c2*w3;
        a3.x += c3*w0; a3.y += c3*w1; a3.z += c3*w2; a3.w += c3*w3;
    }
    XADD(a0); XADD(a1); XADD(a2); XADD(a3);   // combine even/odd-row partials
    if (!hi) {
        *(float4*)(&part[wave][0][4 * q]) = a0;
        *(float4*)(&part[wave][1][4 * q]) = a1;
        *(float4*)(&part[wave][2][4 * q]) = a2;
        *(float4*)(&part[wave][3][4 * q]) = a3;
    }
    __syncthreads();

    // ---- epilogue: combine j-halves + bias + relu + coalesced store
    const int o = tid >> 5, q2 = tid & 31;
    float4 p0 = *(const float4*)(&part[0][o][4 * q2]);
    float4 p1 = *(const float4*)(&part[1][o][4 * q2]);
    float4 v1 = *(const float4*)(b1 + 4 * q2);
    float4 v2 = *(const float4*)(b2 + 4 * q2);
    float4 r;
    r.x = fmaxf(p0.x + p1.x + v1.x + v2.x, 0.f);
    r.y = fmaxf(p0.y + p1.y + v1.y + v2.y, 0.f);
    r.z = fmaxf(p0.z + p1.z + v1.z + v2.z, 0.f);
    r.w = fmaxf(p0.w + p1.w + v1.w + v2.w, 0.f);
    const int orow = blockIdx.x * 4 + o;      // = pair*2 + side
    if (orow < 2 * npair)
        *(float4*)(out + (size_t)orow * ES + 4 * q2) = r;
}

extern "C" void kernel_launch(void* const* d_in, const int* in_sizes, int n_in,
                              void* d_out, int out_size, void* d_ws, size_t ws_size,
                              hipStream_t stream) {
    const float* ent = (const float*)d_in[0];
    const float* rel = (const float*)d_in[1];
    const float* Wb  = (const float*)d_in[2];
    const float* W1  = (const float*)d_in[3];
    const float* b1  = (const float*)d_in[4];
    const float* W2  = (const float*)d_in[5];
    const float* b2  = (const float*)d_in[6];
    const int* hidx  = (const int*)d_in[7];
    const int* tidx  = (const int*)d_in[8];
    const int* conn  = (const int*)d_in[9];
    float* out = (float*)d_out;

    const int npair   = in_sizes[7];          // 4096
    const int num_ent = in_sizes[0] / ES;     // 100000
    const int num_rel = in_sizes[1] / ES;     // 200

    // ws layout: RWb f32 [num_rel*128] = 100 KB ; WTB bf16 [256*128] = 64 KB
    // total 164 KB  (proven bound: 192 KB OK, 233 KB overflows)
    float* rwb = (float*)d_ws;
    unsigned short* wtb = (unsigned short*)(rwb + (size_t)num_rel * ES);

    prep_rwb<<<num_rel, 128, 0, stream>>>(rel, Wb, rwb);
    prep_wtbf<<<(2 * ES * ES) / 256, 256, 0, stream>>>(W1, W2, wtb);

    const int nblocks = (npair + 1) / 2;      // 2 pairs per block (1 per wave)
    onehop_main<<<nblocks, 128, 0, stream>>>(
        ent, rel, b1, b2, hidx, tidx, conn,
        rwb, wtb, out, npair, num_ent, num_rel);
}